// Round 12
// baseline (476.885 us; speedup 1.0000x reference)
//
#include <hip/hip_runtime.h>
#include <stdint.h>

#define NT 512    // 8 waves per block
#define NWAVE 8
#define ROW 8192
#define QPL 32    // u32x4 quads per lane (128 u32 per lane per row)
#define RPW 4     // rows per wave
#define NBIN 256
#define REP 4     // histogram bank-replicas (spread hot bins across 4 banks)

typedef unsigned int u32x4 __attribute__((ext_vector_type(4)));
typedef float f32x4 __attribute__((ext_vector_type(4)));

// Order-preserving float->uint transform (ascending uint == ascending float).
__device__ __forceinline__ uint32_t f2u(uint32_t b) {
    return (b & 0x80000000u) ? ~b : (b | 0x80000000u);
}
__device__ __forceinline__ uint32_t u2fbits(uint32_t u) {
    return (u & 0x80000000u) ? (u ^ 0x80000000u) : ~u;
}
// Wave-local LDS ordering; no __syncthreads in this kernel at all.
__device__ __forceinline__ void lds_fence() {
    asm volatile("s_waitcnt lgkmcnt(0)" ::: "memory");
}

__device__ __forceinline__ void hist_clear(uint32_t* hist, int lane) {
    u32x4 z = {0u, 0u, 0u, 0u};
#pragma unroll
    for (int i = 0; i < (NBIN * REP / 4) / 64; ++i)  // = 4
        ((u32x4*)hist)[i * 64 + lane] = z;
}

// Wave-level 256-bin select. hist[bin*REP+r] replicated counts; higher bin =
// larger value. Finds digit d with cnt(>d) < k <= cnt(>=d); updates k in place.
__device__ __forceinline__ uint32_t wave_select(const uint32_t* hist, int lane,
                                                uint32_t& k_io) {
    // lane covers bins [4*lane .. 4*lane+3]; sum REP replicas per bin
    u32x4 h[4];
#pragma unroll
    for (int i = 0; i < 4; ++i) h[i] = ((const u32x4*)hist)[lane * 4 + i];
    uint32_t b[4], local = 0;
#pragma unroll
    for (int i = 0; i < 4; ++i) {
        b[i] = h[i].x + h[i].y + h[i].z + h[i].w;
        local += b[i];
    }
    // inclusive suffix sum across lanes (lane l: sum over lanes >= l)
    uint32_t incl = local;
#pragma unroll
    for (int off = 1; off < 64; off <<= 1) {
        uint32_t vv = __shfl_down(incl, off, 64);
        if (lane + off < 64) incl += vv;
    }
    const uint32_t k = k_io;
    const uint32_t sfx_excl = incl - local;
    const bool found = (sfx_excl < k) && (k <= incl);
    uint32_t dig = 0, kn = 0;
    if (found) {  // exactly one lane
        uint32_t cum = sfx_excl;
        bool done = false;
#pragma unroll
        for (int i = 3; i >= 0; --i) {
            if (!done) {
                if (k <= cum + b[i]) {
                    dig = (uint32_t)(lane * 4 + i);
                    kn = k - cum;
                    done = true;
                } else {
                    cum += b[i];
                }
            }
        }
    }
    unsigned long long mb = __ballot(found);
    int src = (int)__ffsll(mb) - 1;
    dig = (uint32_t)__shfl((int)dig, src, 64);
    kn = (uint32_t)__shfl((int)kn, src, 64);
    k_io = kn;
    return dig;
}

__global__ __launch_bounds__(NT, 2) void ksparse_rowtopk(const float* __restrict__ x,
                                                         const int* __restrict__ kp,
                                                         float* __restrict__ out,
                                                         int nrows) {
    __shared__ uint32_t s_hist[NWAVE][NBIN * REP];  // 4 KiB per wave = 32 KiB

    const int lane = threadIdx.x & 63;
    const int wv = threadIdx.x >> 6;
    uint32_t* hist = s_hist[wv];
    const int rsel = lane & 3;
    const long long gw = (long long)blockIdx.x * NWAVE + wv;  // global wave id

    int kin = *kp;
    if (kin < 1) kin = 1;
    if (kin > ROW) kin = ROW;
    const uint32_t k0 = (uint32_t)kin;

#pragma unroll 1
    for (int rr = 0; rr < RPW; ++rr) {
        const long long row = gw * RPW + rr;
        if (row >= nrows) break;

        // ---- load row into registers (coalesced 16B/lane, streaming)
        const u32x4* xin = (const u32x4*)(x + row * ROW);
        u32x4 v[QPL];
#pragma unroll
        for (int j = 0; j < QPL; ++j)
            v[j] = __builtin_nontemporal_load(&xin[j * 64 + lane]);
#pragma unroll
        for (int j = 0; j < QPL; ++j) {
            v[j].x = f2u(v[j].x);
            v[j].y = f2u(v[j].y);
            v[j].z = f2u(v[j].z);
            v[j].w = f2u(v[j].w);
        }

        uint32_t k = k0;

        // ---- pass 1: top 8 bits (wave-private hist, no barriers)
        hist_clear(hist, lane);
        lds_fence();
#pragma unroll
        for (int j = 0; j < QPL; ++j) {
            atomicAdd(&hist[(v[j].x >> 24) * REP + rsel], 1u);
            atomicAdd(&hist[(v[j].y >> 24) * REP + rsel], 1u);
            atomicAdd(&hist[(v[j].z >> 24) * REP + rsel], 1u);
            atomicAdd(&hist[(v[j].w >> 24) * REP + rsel], 1u);
        }
        lds_fence();
        uint32_t pfx = wave_select(hist, lane, k);

        // ---- passes 2..4: generic 8-bit refinement on prefix-matched elements
#pragma unroll 1
        for (int p = 0; p < 3; ++p) {
            hist_clear(hist, lane);
            lds_fence();
            const int mshift = 24 - p * 8;  // prefix match field
            const int bshift = 16 - p * 8;  // bin field
#pragma unroll
            for (int j = 0; j < QPL; ++j) {
                if ((v[j].x >> mshift) == pfx)
                    atomicAdd(&hist[((v[j].x >> bshift) & 255u) * REP + rsel], 1u);
                if ((v[j].y >> mshift) == pfx)
                    atomicAdd(&hist[((v[j].y >> bshift) & 255u) * REP + rsel], 1u);
                if ((v[j].z >> mshift) == pfx)
                    atomicAdd(&hist[((v[j].z >> bshift) & 255u) * REP + rsel], 1u);
                if ((v[j].w >> mshift) == pfx)
                    atomicAdd(&hist[((v[j].w >> bshift) & 255u) * REP + rsel], 1u);
            }
            lds_fence();
            const uint32_t d = wave_select(hist, lane, k);
            pfx = (pfx << 8) | d;
        }
        const uint32_t thr = pfx;  // exact uint of the kth-largest value

        // ---- output: keep if u >= thr (== float compare via monotone transform)
        f32x4* orow = (f32x4*)(out + row * ROW);
#pragma unroll
        for (int j = 0; j < QPL; ++j) {
            f32x4 o;
            o.x = (v[j].x >= thr) ? __uint_as_float(u2fbits(v[j].x)) : 0.0f;
            o.y = (v[j].y >= thr) ? __uint_as_float(u2fbits(v[j].y)) : 0.0f;
            o.z = (v[j].z >= thr) ? __uint_as_float(u2fbits(v[j].z)) : 0.0f;
            o.w = (v[j].w >= thr) ? __uint_as_float(u2fbits(v[j].w)) : 0.0f;
            __builtin_nontemporal_store(o, &orow[j * 64 + lane]);
        }
    }
}

extern "C" void kernel_launch(void* const* d_in, const int* in_sizes, int n_in,
                              void* d_out, int out_size, void* d_ws, size_t ws_size,
                              hipStream_t stream) {
    const float* x = (const float*)d_in[0];
    const int* kp = (const int*)d_in[1];
    float* out = (float*)d_out;
    const int rows = in_sizes[0] / ROW;                       // 8192
    const int grid = (rows + NWAVE * RPW - 1) / (NWAVE * RPW);  // 256
    ksparse_rowtopk<<<dim3(grid), dim3(NT), 0, stream>>>(x, kp, out, rows);
}